// Round 2
// baseline (456.243 us; speedup 1.0000x reference)
//
#include <hip/hip_runtime.h>
#include <hip/hip_bf16.h>
#include <cstdint>
#include <cstddef>

#define B_  32
#define T_  2048
#define D_  1024
#define H_  1024
#define M_  (B_ * T_)   // 65536 rows of t

typedef __attribute__((ext_vector_type(4))) float  f32x4;
typedef __attribute__((ext_vector_type(8))) __bf16 bf16x8;

__device__ __forceinline__ unsigned int f2bf(float f) {
  unsigned int u = __float_as_uint(f);
  return (u + 0x7fffu + ((u >> 16) & 1u)) >> 16;   // RNE
}
__device__ __forceinline__ unsigned int packbf2(float lo, float hi) {
  return f2bf(lo) | (f2bf(hi) << 16);
}
__device__ __forceinline__ float fast_tanh(float x) {
  x = fminf(fmaxf(x, -15.f), 15.f);
  float e = __expf(2.f * x);
  return (e - 1.f) / (e + 1.f);
}

// ---------------------------------------------------------------------------
// wt (D x H fp32, row-major) -> wtT (H x D bf16, row-major)  [2 MB out]
// ---------------------------------------------------------------------------
__global__ __launch_bounds__(256) void k_wt_transpose(const float* __restrict__ wt,
                                                      unsigned short* __restrict__ wtT) {
  __shared__ float tile[32][33];
  const int tx = threadIdx.x & 31, ty = threadIdx.x >> 5;  // 32 x 8
  const int c0 = blockIdx.x * 32, r0 = blockIdx.y * 32;
#pragma unroll
  for (int i = 0; i < 4; ++i)
    tile[ty + i * 8][tx] = wt[(size_t)(r0 + ty + i * 8) * H_ + c0 + tx];
  __syncthreads();
#pragma unroll
  for (int i = 0; i < 4; ++i)
    wtT[(size_t)(c0 + ty + i * 8) * D_ + r0 + tx] = (unsigned short)f2bf(tile[tx][ty + i * 8]);
}

// ---------------------------------------------------------------------------
// g[b,h] = tanh(a[b]@wa[:,h]) * tanh(b[b]@wb[:,h]) * wh[h]
// ---------------------------------------------------------------------------
__global__ __launch_bounds__(256) void k_g(const float* __restrict__ a,
                                           const float* __restrict__ b,
                                           const float* __restrict__ wa,
                                           const float* __restrict__ wb,
                                           const float* __restrict__ wh,
                                           float* __restrict__ g) {
  const int idx = blockIdx.x * 256 + threadIdx.x;   // 0 .. 32767
  const int bb = idx >> 10, h = idx & 1023;
  float sa = 0.f, sb = 0.f;
  for (int d = 0; d < 1024; ++d) {
    sa += a[bb * 1024 + d] * wa[d * 1024 + h];
    sb += b[bb * 1024 + d] * wb[d * 1024 + h];
  }
  g[idx] = fast_tanh(sa) * fast_tanh(sb) * wh[h];
}

// ---------------------------------------------------------------------------
// Mask layout detection: read first 16384 int32 words (= 64KB, safe whether
// the mask is 65536 int32 or 65536 bytes). Any word value > 1 => byte-packed
// bools (e.g. 0x00010001). A true int32 {0,1} mask never exceeds 1.
// Deterministic: fixed input contents -> fixed flag.
// ---------------------------------------------------------------------------
__global__ __launch_bounds__(256) void k_maskmode(const unsigned int* __restrict__ mask_w,
                                                  int* __restrict__ flag) {
  __shared__ int sh[4];
  int any = 0;
  for (int i = threadIdx.x; i < 16384; i += 256)
    if (mask_w[i] > 1u) any = 1;
  const int wa = __any(any) ? 1 : 0;
  if ((threadIdx.x & 63) == 0) sh[threadIdx.x >> 6] = wa;
  __syncthreads();
  if (threadIdx.x == 0) flag[0] = sh[0] | sh[1] | sh[2] | sh[3];
}

// ---------------------------------------------------------------------------
// Fused score GEMM: spart[bn][row] = sum_{h in N-block bn} tanh((t@wt)[row,h]) * g[b,h]
// M=65536, N=1024, K=1024. 128x128 tile, BK=64, 4 waves (2x2), mfma 16x16x32 bf16.
// Cross-wave (wn) column-partial reduction goes through LDS `red` (race fix).
// ---------------------------------------------------------------------------
__global__ __launch_bounds__(256) void k_score(const float* __restrict__ t,
                                               const unsigned short* __restrict__ wtT,
                                               const float* __restrict__ g,
                                               float* __restrict__ spart) {
  __shared__ unsigned short As[128 * 72];   // [row][k] bf16, pad 64->72
  __shared__ unsigned short Bs[128 * 72];   // [n][k]  bf16, pad 64->72
  __shared__ float red[256];                // [wn][128 rows]
  const int tid = threadIdx.x;
  const int bm = blockIdx.x, bn = blockIdx.y;
  const int lane = tid & 63, w = tid >> 6;
  const int wm = w >> 1, wn = w & 1;
  const int l15 = lane & 15, lk = lane >> 4;
  const int row0 = bm * 128, col0 = bn * 128;
  const int ar = tid >> 2, ac = (tid & 3) * 16;    // A staging: 64 rows/pass, 16 k/thread
  const int brn = tid >> 1, bco = (tid & 1) * 32;  // B staging: 128 rows, 32 k/thread

  f32x4 acc[4][4] = {};

  for (int kt = 0; kt < 16; ++kt) {
    const int k0 = kt * 64;
    __syncthreads();
    // ---- stage A: t[row0..row0+128][k0..k0+64] fp32 -> bf16 LDS
#pragma unroll
    for (int half = 0; half < 2; ++half) {
      const int r = ar + half * 64;
      const float4* src = (const float4*)(t + (size_t)(row0 + r) * 1024 + k0 + ac);
      float4 v0 = src[0], v1 = src[1], v2 = src[2], v3 = src[3];
      uint4 p0, p1;
      p0.x = packbf2(v0.x, v0.y); p0.y = packbf2(v0.z, v0.w);
      p0.z = packbf2(v1.x, v1.y); p0.w = packbf2(v1.z, v1.w);
      p1.x = packbf2(v2.x, v2.y); p1.y = packbf2(v2.z, v2.w);
      p1.z = packbf2(v3.x, v3.y); p1.w = packbf2(v3.z, v3.w);
      uint4* dst = (uint4*)(&As[r * 72 + ac]);
      dst[0] = p0; dst[1] = p1;
    }
    // ---- stage B: wtT[col0..col0+128][k0..k0+64] bf16 copy
    {
      const uint4* src = (const uint4*)(wtT + (size_t)(col0 + brn) * 1024 + k0 + bco);
      uint4 x0 = src[0], x1 = src[1], x2 = src[2], x3 = src[3];
      uint4* dst = (uint4*)(&Bs[brn * 72 + bco]);
      dst[0] = x0; dst[1] = x1; dst[2] = x2; dst[3] = x3;
    }
    __syncthreads();
    // ---- MFMA over the 64-wide k-tile (2 x K=32)
#pragma unroll
    for (int kf = 0; kf < 2; ++kf) {
      bf16x8 af[4], bfr[4];
#pragma unroll
      for (int mi = 0; mi < 4; ++mi)
        af[mi] = *(const bf16x8*)(&As[(wm * 64 + mi * 16 + l15) * 72 + kf * 32 + lk * 8]);
#pragma unroll
      for (int ni = 0; ni < 4; ++ni)
        bfr[ni] = *(const bf16x8*)(&Bs[(wn * 64 + ni * 16 + l15) * 72 + kf * 32 + lk * 8]);
#pragma unroll
      for (int mi = 0; mi < 4; ++mi)
#pragma unroll
        for (int ni = 0; ni < 4; ++ni)
          acc[mi][ni] = __builtin_amdgcn_mfma_f32_16x16x32_bf16(af[mi], bfr[ni], acc[mi][ni], 0, 0, 0);
    }
  }

  // ---- epilogue: tanh, * g[b,h], reduce over this block's 128 h-columns
  const int b = row0 >> 11;  // T=2048, tile never crosses a b-boundary
  float gv[4];
#pragma unroll
  for (int ni = 0; ni < 4; ++ni)
    gv[ni] = g[b * H_ + col0 + wn * 64 + ni * 16 + l15];
#pragma unroll
  for (int mi = 0; mi < 4; ++mi) {
#pragma unroll
    for (int r = 0; r < 4; ++r) {
      float s = 0.f;
#pragma unroll
      for (int ni = 0; ni < 4; ++ni)
        s += fast_tanh(acc[mi][ni][r]) * gv[ni];
      // reduce across the 16 lanes (l15) holding this wave's 64 columns
      s += __shfl_xor(s, 1); s += __shfl_xor(s, 2);
      s += __shfl_xor(s, 4); s += __shfl_xor(s, 8);
      if (l15 == 0)
        red[wn * 128 + wm * 64 + mi * 16 + lk * 4 + r] = s;
    }
  }
  __syncthreads();
  // combine the two wn column-halves (this was the race: both wn waves used
  // to write the same spart rows directly, each with only half the columns)
  if (tid < 128)
    spart[(size_t)bn * M_ + row0 + tid] = red[tid] + red[128 + tid];
}

// ---------------------------------------------------------------------------
// Softmax + mask + renormalize.  att = m * e^{s-max} / sum(m * e^{s-max})
// (unmasked softmax denominator cancels in the renormalization)
// ---------------------------------------------------------------------------
__global__ __launch_bounds__(256) void k_softmax(const float* __restrict__ spart,
                                                 const void* __restrict__ mask,
                                                 const int* __restrict__ mflag,
                                                 float* __restrict__ att) {
  __shared__ float redmax[4], redsum[4];
  const int b = blockIdx.x, tid = threadIdx.x;
  const int byte_mode = mflag[0];
  float s[8];
#pragma unroll
  for (int j = 0; j < 8; ++j) {
    const int idx = tid + j * 256;
    float v = 0.f;
#pragma unroll
    for (int nb = 0; nb < 8; ++nb) v += spart[(size_t)nb * M_ + b * T_ + idx];
    s[j] = v;
  }
  float mx = s[0];
#pragma unroll
  for (int j = 1; j < 8; ++j) mx = fmaxf(mx, s[j]);
  for (int o = 1; o < 64; o <<= 1) mx = fmaxf(mx, __shfl_xor(mx, o));
  if ((tid & 63) == 0) redmax[tid >> 6] = mx;
  __syncthreads();
  mx = fmaxf(fmaxf(redmax[0], redmax[1]), fmaxf(redmax[2], redmax[3]));

  float e[8];
  float sum = 0.f;
#pragma unroll
  for (int j = 0; j < 8; ++j) {
    const int idx = tid + j * 256;
    float v = __expf(s[j] - mx);
    const int mv = byte_mode ? (int)((const unsigned char*)mask)[b * T_ + idx]
                             : ((const int*)mask)[b * T_ + idx];
    v = (mv != 0) ? v : 0.f;
    e[j] = v;
    sum += v;
  }
  for (int o = 1; o < 64; o <<= 1) sum += __shfl_xor(sum, o);
  if ((tid & 63) == 0) redsum[tid >> 6] = sum;
  __syncthreads();
  sum = redsum[0] + redsum[1] + redsum[2] + redsum[3];
  const float inv = 1.f / sum;
#pragma unroll
  for (int j = 0; j < 8; ++j)
    att[b * T_ + tid + j * 256] = e[j] * inv;
}

// ---------------------------------------------------------------------------
// Pooling: pp[tc][b][d] = sum_{t in chunk tc} att[b,t] * t[b,t,d]   (fp32)
// ---------------------------------------------------------------------------
__global__ __launch_bounds__(256) void k_pool(const float* __restrict__ t,
                                              const float* __restrict__ att,
                                              float* __restrict__ pp) {
  const int b = blockIdx.x, tc = blockIdx.y, tid = threadIdx.x;
  const float4* tp = (const float4*)t;
  float4 acc = make_float4(0.f, 0.f, 0.f, 0.f);
  const int tbase = tc * 128;
  for (int i = 0; i < 128; ++i) {
    const int ti = tbase + i;
    const float w = att[b * T_ + ti];
    const float4 v = tp[(size_t)(b * T_ + ti) * 256 + tid];
    acc.x += w * v.x; acc.y += w * v.y; acc.z += w * v.z; acc.w += w * v.w;
  }
  ((float4*)pp)[(size_t)tc * 8192 + b * 256 + tid] = acc;
}

__global__ __launch_bounds__(256) void k_pool_reduce(const float* __restrict__ pp,
                                                     float* __restrict__ out) {
  const int idx = blockIdx.x * 256 + threadIdx.x;  // 0 .. 32767
  float s = 0.f;
#pragma unroll
  for (int tc = 0; tc < 16; ++tc) s += pp[tc * 32768 + idx];
  out[idx] = s;
}

// ---------------------------------------------------------------------------
extern "C" void kernel_launch(void* const* d_in, const int* in_sizes, int n_in,
                              void* d_out, int out_size, void* d_ws, size_t ws_size,
                              hipStream_t stream) {
  const float* t    = (const float*)d_in[0];
  const float* a    = (const float*)d_in[1];
  const float* b    = (const float*)d_in[2];
  const void*  mask = d_in[3];
  const float* wt   = (const float*)d_in[4];
  const float* wa   = (const float*)d_in[5];
  const float* wb   = (const float*)d_in[6];
  const float* wh   = (const float*)d_in[7];
  float* out = (float*)d_out;

  // ws layout (floats): g[32768] | att[65536] | spart[8*65536] | pp[16*32768]
  //                     | wtT (1M ushort = 524288 floats) | mflag[1]
  float* ws    = (float*)d_ws;
  float* g     = ws;
  float* att   = ws + 32768;
  float* spart = ws + 98304;
  float* pp    = ws + 622592;
  unsigned short* wtT = (unsigned short*)(ws + 1146880);
  int* mflag   = (int*)(ws + 1671168);

  k_maskmode<<<1, 256, 0, stream>>>((const unsigned int*)mask, mflag);
  k_wt_transpose<<<dim3(32, 32), 256, 0, stream>>>(wt, wtT);
  k_g<<<128, 256, 0, stream>>>(a, b, wa, wb, wh, g);
  k_score<<<dim3(512, 8), 256, 0, stream>>>(t, wtT, g, spart);
  k_softmax<<<32, 256, 0, stream>>>(spart, mask, mflag, att);
  k_pool<<<dim3(32, 16), 256, 0, stream>>>(t, att, pp);
  k_pool_reduce<<<128, 256, 0, stream>>>(pp, out);
}

// Round 3
// 430.270 us; speedup vs baseline: 1.0604x; 1.0604x over previous
//
#include <hip/hip_runtime.h>
#include <hip/hip_bf16.h>
#include <cstdint>
#include <cstddef>

#define B_  32
#define T_  2048
#define D_  1024
#define H_  1024
#define M_  (B_ * T_)   // 65536 rows of t

typedef __attribute__((ext_vector_type(4))) float  f32x4;
typedef __attribute__((ext_vector_type(8))) __bf16 bf16x8;

#define GLOBAL_AS __attribute__((address_space(1)))
#define LDS_AS    __attribute__((address_space(3)))

__device__ __forceinline__ void gload_lds16(const void* g, void* l) {
  __builtin_amdgcn_global_load_lds((const GLOBAL_AS unsigned int*)g,
                                   (LDS_AS unsigned int*)l, 16, 0, 0);
}

__device__ __forceinline__ unsigned int f2bf(float f) {
  unsigned int u = __float_as_uint(f);
  return (u + 0x7fffu + ((u >> 16) & 1u)) >> 16;   // RNE
}
__device__ __forceinline__ unsigned int packbf2(float lo, float hi) {
  return f2bf(lo) | (f2bf(hi) << 16);
}
__device__ __forceinline__ float fast_tanh(float x) {
  x = fminf(fmaxf(x, -15.f), 15.f);
  float e = __expf(2.f * x);
  return (e - 1.f) / (e + 1.f);
}

// ---------------------------------------------------------------------------
// t (fp32) -> t_bf16, memory-bound streaming pass. 64M elements.
// ---------------------------------------------------------------------------
__global__ __launch_bounds__(256) void k_tobf16(const float4* __restrict__ t4,
                                                uint2* __restrict__ ob) {
  const size_t stride = (size_t)gridDim.x * 256;
  for (size_t i = (size_t)blockIdx.x * 256 + threadIdx.x; i < (size_t)M_ * 256; i += stride) {
    const float4 v = t4[i];
    uint2 o; o.x = packbf2(v.x, v.y); o.y = packbf2(v.z, v.w);
    ob[i] = o;
  }
}

// ---------------------------------------------------------------------------
// wt (D x H fp32, row-major) -> wtT (H x D bf16, row-major)  [2 MB out]
// ---------------------------------------------------------------------------
__global__ __launch_bounds__(256) void k_wt_transpose(const float* __restrict__ wt,
                                                      unsigned short* __restrict__ wtT) {
  __shared__ float tile[32][33];
  const int tx = threadIdx.x & 31, ty = threadIdx.x >> 5;  // 32 x 8
  const int c0 = blockIdx.x * 32, r0 = blockIdx.y * 32;
#pragma unroll
  for (int i = 0; i < 4; ++i)
    tile[ty + i * 8][tx] = wt[(size_t)(r0 + ty + i * 8) * H_ + c0 + tx];
  __syncthreads();
#pragma unroll
  for (int i = 0; i < 4; ++i)
    wtT[(size_t)(c0 + ty + i * 8) * D_ + r0 + tx] = (unsigned short)f2bf(tile[tx][ty + i * 8]);
}

// ---------------------------------------------------------------------------
// g[b,h] = tanh(a[b]@wa[:,h]) * tanh(b[b]@wb[:,h]) * wh[h]
// ---------------------------------------------------------------------------
__global__ __launch_bounds__(256) void k_g(const float* __restrict__ a,
                                           const float* __restrict__ b,
                                           const float* __restrict__ wa,
                                           const float* __restrict__ wb,
                                           const float* __restrict__ wh,
                                           float* __restrict__ g) {
  const int idx = blockIdx.x * 256 + threadIdx.x;   // 0 .. 32767
  const int bb = idx >> 10, h = idx & 1023;
  float sa = 0.f, sb = 0.f;
  for (int d = 0; d < 1024; ++d) {
    sa += a[bb * 1024 + d] * wa[d * 1024 + h];
    sb += b[bb * 1024 + d] * wb[d * 1024 + h];
  }
  g[idx] = fast_tanh(sa) * fast_tanh(sb) * wh[h];
}

// ---------------------------------------------------------------------------
// Mask layout detection (int32 {0,1} vs byte-packed bools).
// ---------------------------------------------------------------------------
__global__ __launch_bounds__(256) void k_maskmode(const unsigned int* __restrict__ mask_w,
                                                  int* __restrict__ flag) {
  __shared__ int sh[4];
  int any = 0;
  for (int i = threadIdx.x; i < 16384; i += 256)
    if (mask_w[i] > 1u) any = 1;
  const int wa = __any(any) ? 1 : 0;
  if ((threadIdx.x & 63) == 0) sh[threadIdx.x >> 6] = wa;
  __syncthreads();
  if (threadIdx.x == 0) flag[0] = sh[0] | sh[1] | sh[2] | sh[3];
}

// ---------------------------------------------------------------------------
// FAST fused score GEMM (m97 structure): spart[bn][row] =
//   sum_{h in N-block bn} tanh((t@wt)[row,h]) * g[b,h]
// 128x128 tile, BK=64, 4 waves (2x2), global_load_lds width-16 staging,
// linear LDS (required by global_load_lds), mfma 16x16x32 bf16.
// Grid: (bn=8 fast, bm=512) so the 8 bn-blocks sharing one A-tile run
// adjacently -> t_bf16 read ~once from HBM (L2/L3 shared).
// ---------------------------------------------------------------------------
__global__ __launch_bounds__(256) void k_score_fast(const unsigned short* __restrict__ tb,
                                                    const unsigned short* __restrict__ wtT,
                                                    const float* __restrict__ g,
                                                    float* __restrict__ spart) {
  __shared__ unsigned short As[128 * 64];   // [row][k] bf16, linear
  __shared__ unsigned short Bs[128 * 64];   // [n][k]  bf16, linear
  __shared__ float red[256];                // [wn][128 rows]
  const int tid = threadIdx.x;
  const int bn = blockIdx.x, bm = blockIdx.y;
  const int lane = tid & 63, w = tid >> 6;
  const int wm = w >> 1, wn = w & 1;
  const int l15 = lane & 15, lk = lane >> 4;
  const int row0 = bm * 128, col0 = bn * 128;

  // staging map: wave w, issue i covers rows w*32 + i*8 + (lane>>3),
  // 16B col-chunk (lane&7) of the 128-B k-row. LDS dest is wave-uniform.
  const int srow = w * 32 + (lane >> 3);
  const int scol = (lane & 7) * 8;                       // elements
  const unsigned short* gA = tb  + (size_t)(row0 + srow) * 1024 + scol;
  const unsigned short* gB = wtT + (size_t)(col0 + srow) * 1024 + scol;
  unsigned short* lA = &As[(w * 32) * 64];
  unsigned short* lB = &Bs[(w * 32) * 64];

  f32x4 acc[4][4] = {};

  for (int kt = 0; kt < 16; ++kt) {
    const int k0 = kt * 64;
    __syncthreads();   // LDS consumed by all waves
#pragma unroll
    for (int i = 0; i < 4; ++i) {
      gload_lds16(gA + (size_t)i * 8192 + k0, lA + i * 512);
      gload_lds16(gB + (size_t)i * 8192 + k0, lB + i * 512);
    }
    __syncthreads();   // compiler drains vmcnt(0) before this barrier
#pragma unroll
    for (int kf = 0; kf < 2; ++kf) {
      bf16x8 af[4], bfr[4];
#pragma unroll
      for (int mi = 0; mi < 4; ++mi)
        af[mi] = *(const bf16x8*)(&As[(wm * 64 + mi * 16 + l15) * 64 + kf * 32 + lk * 8]);
#pragma unroll
      for (int ni = 0; ni < 4; ++ni)
        bfr[ni] = *(const bf16x8*)(&Bs[(wn * 64 + ni * 16 + l15) * 64 + kf * 32 + lk * 8]);
#pragma unroll
      for (int mi = 0; mi < 4; ++mi)
#pragma unroll
        for (int ni = 0; ni < 4; ++ni)
          acc[mi][ni] = __builtin_amdgcn_mfma_f32_16x16x32_bf16(af[mi], bfr[ni], acc[mi][ni], 0, 0, 0);
    }
  }

  // ---- epilogue: tanh, * g[b,h], reduce over this block's 128 h-columns
  const int b = row0 >> 11;  // T=2048, tile never crosses a b-boundary
  float gv[4];
#pragma unroll
  for (int ni = 0; ni < 4; ++ni)
    gv[ni] = g[b * H_ + col0 + wn * 64 + ni * 16 + l15];
#pragma unroll
  for (int mi = 0; mi < 4; ++mi) {
#pragma unroll
    for (int r = 0; r < 4; ++r) {
      float s = 0.f;
#pragma unroll
      for (int ni = 0; ni < 4; ++ni)
        s += fast_tanh(acc[mi][ni][r]) * gv[ni];
      s += __shfl_xor(s, 1); s += __shfl_xor(s, 2);
      s += __shfl_xor(s, 4); s += __shfl_xor(s, 8);
      if (l15 == 0)
        red[wn * 128 + wm * 64 + mi * 16 + lk * 4 + r] = s;
    }
  }
  __syncthreads();
  if (tid < 128)
    spart[(size_t)bn * M_ + row0 + tid] = red[tid] + red[128 + tid];
}

// ---------------------------------------------------------------------------
// Fallback fused score GEMM (reg-staged fp32->bf16), used if ws too small.
// ---------------------------------------------------------------------------
__global__ __launch_bounds__(256) void k_score_rs(const float* __restrict__ t,
                                                  const unsigned short* __restrict__ wtT,
                                                  const float* __restrict__ g,
                                                  float* __restrict__ spart) {
  __shared__ unsigned short As[128 * 72];
  __shared__ unsigned short Bs[128 * 72];
  __shared__ float red[256];
  const int tid = threadIdx.x;
  const int bn = blockIdx.x, bm = blockIdx.y;
  const int lane = tid & 63, w = tid >> 6;
  const int wm = w >> 1, wn = w & 1;
  const int l15 = lane & 15, lk = lane >> 4;
  const int row0 = bm * 128, col0 = bn * 128;
  const int ar = tid >> 2, ac = (tid & 3) * 16;
  const int brn = tid >> 1, bco = (tid & 1) * 32;

  f32x4 acc[4][4] = {};

  for (int kt = 0; kt < 16; ++kt) {
    const int k0 = kt * 64;
    __syncthreads();
#pragma unroll
    for (int half = 0; half < 2; ++half) {
      const int r = ar + half * 64;
      const float4* src = (const float4*)(t + (size_t)(row0 + r) * 1024 + k0 + ac);
      float4 v0 = src[0], v1 = src[1], v2 = src[2], v3 = src[3];
      uint4 p0, p1;
      p0.x = packbf2(v0.x, v0.y); p0.y = packbf2(v0.z, v0.w);
      p0.z = packbf2(v1.x, v1.y); p0.w = packbf2(v1.z, v1.w);
      p1.x = packbf2(v2.x, v2.y); p1.y = packbf2(v2.z, v2.w);
      p1.z = packbf2(v3.x, v3.y); p1.w = packbf2(v3.z, v3.w);
      uint4* dst = (uint4*)(&As[r * 72 + ac]);
      dst[0] = p0; dst[1] = p1;
    }
    {
      const uint4* src = (const uint4*)(wtT + (size_t)(col0 + brn) * 1024 + k0 + bco);
      uint4 x0 = src[0], x1 = src[1], x2 = src[2], x3 = src[3];
      uint4* dst = (uint4*)(&Bs[brn * 72 + bco]);
      dst[0] = x0; dst[1] = x1; dst[2] = x2; dst[3] = x3;
    }
    __syncthreads();
#pragma unroll
    for (int kf = 0; kf < 2; ++kf) {
      bf16x8 af[4], bfr[4];
#pragma unroll
      for (int mi = 0; mi < 4; ++mi)
        af[mi] = *(const bf16x8*)(&As[(wm * 64 + mi * 16 + l15) * 72 + kf * 32 + lk * 8]);
#pragma unroll
      for (int ni = 0; ni < 4; ++ni)
        bfr[ni] = *(const bf16x8*)(&Bs[(wn * 64 + ni * 16 + l15) * 72 + kf * 32 + lk * 8]);
#pragma unroll
      for (int mi = 0; mi < 4; ++mi)
#pragma unroll
        for (int ni = 0; ni < 4; ++ni)
          acc[mi][ni] = __builtin_amdgcn_mfma_f32_16x16x32_bf16(af[mi], bfr[ni], acc[mi][ni], 0, 0, 0);
    }
  }

  const int b = row0 >> 11;
  float gv[4];
#pragma unroll
  for (int ni = 0; ni < 4; ++ni)
    gv[ni] = g[b * H_ + col0 + wn * 64 + ni * 16 + l15];
#pragma unroll
  for (int mi = 0; mi < 4; ++mi) {
#pragma unroll
    for (int r = 0; r < 4; ++r) {
      float s = 0.f;
#pragma unroll
      for (int ni = 0; ni < 4; ++ni)
        s += fast_tanh(acc[mi][ni][r]) * gv[ni];
      s += __shfl_xor(s, 1); s += __shfl_xor(s, 2);
      s += __shfl_xor(s, 4); s += __shfl_xor(s, 8);
      if (l15 == 0)
        red[wn * 128 + wm * 64 + mi * 16 + lk * 4 + r] = s;
    }
  }
  __syncthreads();
  if (tid < 128)
    spart[(size_t)bn * M_ + row0 + tid] = red[tid] + red[128 + tid];
}

// ---------------------------------------------------------------------------
// Softmax + mask + renormalize.
// ---------------------------------------------------------------------------
__global__ __launch_bounds__(256) void k_softmax(const float* __restrict__ spart,
                                                 const void* __restrict__ mask,
                                                 const int* __restrict__ mflag,
                                                 float* __restrict__ att) {
  __shared__ float redmax[4], redsum[4];
  const int b = blockIdx.x, tid = threadIdx.x;
  const int byte_mode = mflag[0];
  float s[8];
#pragma unroll
  for (int j = 0; j < 8; ++j) {
    const int idx = tid + j * 256;
    float v = 0.f;
#pragma unroll
    for (int nb = 0; nb < 8; ++nb) v += spart[(size_t)nb * M_ + b * T_ + idx];
    s[j] = v;
  }
  float mx = s[0];
#pragma unroll
  for (int j = 1; j < 8; ++j) mx = fmaxf(mx, s[j]);
  for (int o = 1; o < 64; o <<= 1) mx = fmaxf(mx, __shfl_xor(mx, o));
  if ((tid & 63) == 0) redmax[tid >> 6] = mx;
  __syncthreads();
  mx = fmaxf(fmaxf(redmax[0], redmax[1]), fmaxf(redmax[2], redmax[3]));

  float e[8];
  float sum = 0.f;
#pragma unroll
  for (int j = 0; j < 8; ++j) {
    const int idx = tid + j * 256;
    float v = __expf(s[j] - mx);
    const int mv = byte_mode ? (int)((const unsigned char*)mask)[b * T_ + idx]
                             : ((const int*)mask)[b * T_ + idx];
    v = (mv != 0) ? v : 0.f;
    e[j] = v;
    sum += v;
  }
  for (int o = 1; o < 64; o <<= 1) sum += __shfl_xor(sum, o);
  if ((tid & 63) == 0) redsum[tid >> 6] = sum;
  __syncthreads();
  sum = redsum[0] + redsum[1] + redsum[2] + redsum[3];
  const float inv = 1.f / sum;
#pragma unroll
  for (int j = 0; j < 8; ++j)
    att[b * T_ + tid + j * 256] = e[j] * inv;
}

// ---------------------------------------------------------------------------
// Pooling (fp32 t for precision): pp[tc][b][d] = sum_{t in chunk} att * t
// ---------------------------------------------------------------------------
__global__ __launch_bounds__(256) void k_pool(const float* __restrict__ t,
                                              const float* __restrict__ att,
                                              float* __restrict__ pp) {
  const int b = blockIdx.x, tc = blockIdx.y, tid = threadIdx.x;
  const float4* tp = (const float4*)t;
  float4 acc = make_float4(0.f, 0.f, 0.f, 0.f);
  const int tbase = tc * 128;
  for (int i = 0; i < 128; ++i) {
    const int ti = tbase + i;
    const float w = att[b * T_ + ti];
    const float4 v = tp[(size_t)(b * T_ + ti) * 256 + tid];
    acc.x += w * v.x; acc.y += w * v.y; acc.z += w * v.z; acc.w += w * v.w;
  }
  ((float4*)pp)[(size_t)tc * 8192 + b * 256 + tid] = acc;
}

__global__ __launch_bounds__(256) void k_pool_reduce(const float* __restrict__ pp,
                                                     float* __restrict__ out) {
  const int idx = blockIdx.x * 256 + threadIdx.x;  // 0 .. 32767
  float s = 0.f;
#pragma unroll
  for (int tc = 0; tc < 16; ++tc) s += pp[tc * 32768 + idx];
  out[idx] = s;
}

// ---------------------------------------------------------------------------
extern "C" void kernel_launch(void* const* d_in, const int* in_sizes, int n_in,
                              void* d_out, int out_size, void* d_ws, size_t ws_size,
                              hipStream_t stream) {
  const float* t    = (const float*)d_in[0];
  const float* a    = (const float*)d_in[1];
  const float* b    = (const float*)d_in[2];
  const void*  mask = d_in[3];
  const float* wt   = (const float*)d_in[4];
  const float* wa   = (const float*)d_in[5];
  const float* wb   = (const float*)d_in[6];
  const float* wh   = (const float*)d_in[7];
  float* out = (float*)d_out;

  // fast ws layout (float units):
  //   tb[33554432] | g[32768] | att[65536] | spart[524288] | pp[524288]
  //   | wtT[524288] | mflag
  float* ws = (float*)d_ws;
  const size_t NEED_FAST = (size_t)(33554432 + 32768 + 65536 + 524288 + 524288 + 524288 + 4) * 4;
  const bool fast = ws_size >= NEED_FAST;

  if (fast) {
    unsigned short* tb = (unsigned short*)ws;
    float* g     = ws + 33554432;
    float* att   = g + 32768;
    float* spart = att + 65536;
    float* pp    = spart + 524288;
    unsigned short* wtT = (unsigned short*)(pp + 524288);
    int* mflag   = (int*)(pp + 524288 + 524288);

    k_maskmode<<<1, 256, 0, stream>>>((const unsigned int*)mask, mflag);
    k_wt_transpose<<<dim3(32, 32), 256, 0, stream>>>(wt, wtT);
    k_tobf16<<<4096, 256, 0, stream>>>((const float4*)t, (uint2*)tb);
    k_g<<<128, 256, 0, stream>>>(a, b, wa, wb, wh, g);
    k_score_fast<<<dim3(8, 512), 256, 0, stream>>>(tb, wtT, g, spart);
    k_softmax<<<32, 256, 0, stream>>>(spart, mask, mflag, att);
    k_pool<<<dim3(32, 16), 256, 0, stream>>>(t, att, pp);
    k_pool_reduce<<<128, 256, 0, stream>>>(pp, out);
  } else {
    float* g     = ws;
    float* att   = ws + 32768;
    float* spart = ws + 98304;
    float* pp    = ws + 622592;
    unsigned short* wtT = (unsigned short*)(ws + 1146880);
    int* mflag   = (int*)(ws + 1671168);

    k_maskmode<<<1, 256, 0, stream>>>((const unsigned int*)mask, mflag);
    k_wt_transpose<<<dim3(32, 32), 256, 0, stream>>>(wt, wtT);
    k_g<<<128, 256, 0, stream>>>(a, b, wa, wb, wh, g);
    k_score_rs<<<dim3(8, 512), 256, 0, stream>>>(t, wtT, g, spart);
    k_softmax<<<32, 256, 0, stream>>>(spart, mask, mflag, att);
    k_pool<<<dim3(32, 16), 256, 0, stream>>>(t, att, pp);
    k_pool_reduce<<<128, 256, 0, stream>>>(pp, out);
  }
}

// Round 4
// 378.820 us; speedup vs baseline: 1.2044x; 1.1358x over previous
//
#include <hip/hip_runtime.h>
#include <hip/hip_bf16.h>
#include <cstdint>
#include <cstddef>

#define B_  32
#define T_  2048
#define D_  1024
#define H_  1024
#define M_  (B_ * T_)   // 65536 rows of t

typedef __attribute__((ext_vector_type(4))) float  f32x4;
typedef __attribute__((ext_vector_type(8))) __bf16 bf16x8;

#define GLOBAL_AS __attribute__((address_space(1)))
#define LDS_AS    __attribute__((address_space(3)))

__device__ __forceinline__ void gload_lds16(const void* g, void* l) {
  __builtin_amdgcn_global_load_lds((const GLOBAL_AS unsigned int*)g,
                                   (LDS_AS unsigned int*)l, 16, 0, 0);
}

__device__ __forceinline__ unsigned int f2bf(float f) {
  unsigned int u = __float_as_uint(f);
  return (u + 0x7fffu + ((u >> 16) & 1u)) >> 16;   // RNE
}
__device__ __forceinline__ unsigned int packbf2(float lo, float hi) {
  return f2bf(lo) | (f2bf(hi) << 16);
}
__device__ __forceinline__ float bfu(unsigned int u) {   // bf16 bits (low 16) -> f32
  return __uint_as_float(u << 16);
}
__device__ __forceinline__ float fast_tanh(float x) {
  x = fminf(fmaxf(x, -15.f), 15.f);
  float e = __expf(2.f * x);
  return (e - 1.f) / (e + 1.f);
}

// ---------------------------------------------------------------------------
// t (fp32) -> t_bf16, memory-bound streaming pass. 64M elements.
// ---------------------------------------------------------------------------
__global__ __launch_bounds__(256) void k_tobf16(const float4* __restrict__ t4,
                                                uint2* __restrict__ ob) {
  const size_t stride = (size_t)gridDim.x * 256;
  for (size_t i = (size_t)blockIdx.x * 256 + threadIdx.x; i < (size_t)M_ * 256; i += stride) {
    const float4 v = t4[i];
    uint2 o; o.x = packbf2(v.x, v.y); o.y = packbf2(v.z, v.w);
    ob[i] = o;
  }
}

// ---------------------------------------------------------------------------
// wt (D x H fp32, row-major) -> wtT (H x D bf16, row-major)  [2 MB out]
// ---------------------------------------------------------------------------
__global__ __launch_bounds__(256) void k_wt_transpose(const float* __restrict__ wt,
                                                      unsigned short* __restrict__ wtT) {
  __shared__ float tile[32][33];
  const int tx = threadIdx.x & 31, ty = threadIdx.x >> 5;  // 32 x 8
  const int c0 = blockIdx.x * 32, r0 = blockIdx.y * 32;
#pragma unroll
  for (int i = 0; i < 4; ++i)
    tile[ty + i * 8][tx] = wt[(size_t)(r0 + ty + i * 8) * H_ + c0 + tx];
  __syncthreads();
#pragma unroll
  for (int i = 0; i < 4; ++i)
    wtT[(size_t)(c0 + ty + i * 8) * D_ + r0 + tx] = (unsigned short)f2bf(tile[tx][ty + i * 8]);
}

// ---------------------------------------------------------------------------
// g[b,h] = tanh(a[b]@wa[:,h]) * tanh(b[b]@wb[:,h]) * wh[h]
// ---------------------------------------------------------------------------
__global__ __launch_bounds__(256) void k_g(const float* __restrict__ a,
                                           const float* __restrict__ b,
                                           const float* __restrict__ wa,
                                           const float* __restrict__ wb,
                                           const float* __restrict__ wh,
                                           float* __restrict__ g) {
  const int idx = blockIdx.x * 256 + threadIdx.x;   // 0 .. 32767
  const int bb = idx >> 10, h = idx & 1023;
  float sa = 0.f, sb = 0.f;
  for (int d = 0; d < 1024; ++d) {
    sa += a[bb * 1024 + d] * wa[d * 1024 + h];
    sb += b[bb * 1024 + d] * wb[d * 1024 + h];
  }
  g[idx] = fast_tanh(sa) * fast_tanh(sb) * wh[h];
}

// ---------------------------------------------------------------------------
// FAST fused score GEMM: 256x128 tile, BK=64, 8 waves (4M x 2N), 512 threads.
// global_load_lds width-16 staging, linear LDS, mfma 16x16x32 bf16.
// XCD-bijective swizzle: 2048 wgs, XCD k owns work [k*256,(k+1)*256) =
// bm2 in [k*32,k*32+32) x all bn -> each A-panel fetched ~once per XCD L2.
// spart[bn][row] = sum_{h in bn-block} tanh((t@wt)[row,h]) * g[b,h]
// ---------------------------------------------------------------------------
__global__ __launch_bounds__(512) void k_score_fast(const unsigned short* __restrict__ tb,
                                                    const unsigned short* __restrict__ wtT,
                                                    const float* __restrict__ g,
                                                    float* __restrict__ spart) {
  __shared__ unsigned short As[256 * 64];   // 32 KB  [row][k] linear
  __shared__ unsigned short Bs[128 * 64];   // 16 KB  [n][k]  linear
  __shared__ float red[512];                // [wn][256 rows]
  const int tid = threadIdx.x;
  const int wg  = (blockIdx.x & 7) * 256 + (blockIdx.x >> 3);  // bijective, 2048%8==0
  const int bm2 = wg >> 3, bn = wg & 7;
  const int lane = tid & 63, w = tid >> 6;       // 8 waves
  const int wm = w >> 1, wn = w & 1;             // 4 x 2
  const int l15 = lane & 15, lk = lane >> 4;
  const int row0 = bm2 * 256, col0 = bn * 128;

  // staging: wave-uniform LDS base + lane*16B contiguous (gload_lds requirement)
  const int srow = lane >> 3;                    // 8 rows per 1KB issue
  const int scol = (lane & 7) * 8;               // 16B chunk within 128B row
  const unsigned short* gA = tb  + (size_t)(row0 + w * 32 + srow) * 1024 + scol;
  const unsigned short* gB = wtT + (size_t)(col0 + w * 16 + srow) * 1024 + scol;
  unsigned short* lA = &As[(w * 32) * 64];
  unsigned short* lB = &Bs[(w * 16) * 64];

  f32x4 acc[4][4] = {};

  for (int kt = 0; kt < 16; ++kt) {
    const int k0 = kt * 64;
    __syncthreads();   // previous iteration's LDS reads done
#pragma unroll
    for (int i = 0; i < 4; ++i)   // A: rows w*32 + i*8 .. +8
      gload_lds16(gA + (size_t)i * 8192 + k0, lA + i * 512);
#pragma unroll
    for (int j = 0; j < 2; ++j)   // B: rows w*16 + j*8 .. +8
      gload_lds16(gB + (size_t)j * 8192 + k0, lB + j * 512);
    __syncthreads();   // compiler drains vmcnt(0) before this barrier
#pragma unroll
    for (int kf = 0; kf < 2; ++kf) {
      bf16x8 af[4], bfr[4];
#pragma unroll
      for (int mi = 0; mi < 4; ++mi)
        af[mi] = *(const bf16x8*)(&As[(wm * 64 + mi * 16 + l15) * 64 + kf * 32 + lk * 8]);
#pragma unroll
      for (int ni = 0; ni < 4; ++ni)
        bfr[ni] = *(const bf16x8*)(&Bs[(wn * 64 + ni * 16 + l15) * 64 + kf * 32 + lk * 8]);
#pragma unroll
      for (int mi = 0; mi < 4; ++mi)
#pragma unroll
        for (int ni = 0; ni < 4; ++ni)
          acc[mi][ni] = __builtin_amdgcn_mfma_f32_16x16x32_bf16(af[mi], bfr[ni], acc[mi][ni], 0, 0, 0);
    }
  }

  // ---- epilogue: tanh, * g[b,h], reduce over this block's 128 h-columns
  const int b = row0 >> 11;  // 256-row tile never crosses a b-boundary
  float gv[4];
#pragma unroll
  for (int ni = 0; ni < 4; ++ni)
    gv[ni] = g[b * H_ + col0 + wn * 64 + ni * 16 + l15];
#pragma unroll
  for (int mi = 0; mi < 4; ++mi) {
#pragma unroll
    for (int r = 0; r < 4; ++r) {
      float s = 0.f;
#pragma unroll
      for (int ni = 0; ni < 4; ++ni)
        s += fast_tanh(acc[mi][ni][r]) * gv[ni];
      s += __shfl_xor(s, 1); s += __shfl_xor(s, 2);
      s += __shfl_xor(s, 4); s += __shfl_xor(s, 8);
      if (l15 == 0)
        red[wn * 256 + wm * 64 + mi * 16 + lk * 4 + r] = s;
    }
  }
  __syncthreads();
  if (tid < 256)
    spart[(size_t)bn * M_ + row0 + tid] = red[tid] + red[256 + tid];
}

// ---------------------------------------------------------------------------
// Fallback fused score GEMM (reg-staged fp32->bf16), used if ws too small.
// ---------------------------------------------------------------------------
__global__ __launch_bounds__(256) void k_score_rs(const float* __restrict__ t,
                                                  const unsigned short* __restrict__ wtT,
                                                  const float* __restrict__ g,
                                                  float* __restrict__ spart) {
  __shared__ unsigned short As[128 * 72];
  __shared__ unsigned short Bs[128 * 72];
  __shared__ float red[256];
  const int tid = threadIdx.x;
  const int bn = blockIdx.x, bm = blockIdx.y;
  const int lane = tid & 63, w = tid >> 6;
  const int wm = w >> 1, wn = w & 1;
  const int l15 = lane & 15, lk = lane >> 4;
  const int row0 = bm * 128, col0 = bn * 128;
  const int ar = tid >> 2, ac = (tid & 3) * 16;
  const int brn = tid >> 1, bco = (tid & 1) * 32;

  f32x4 acc[4][4] = {};

  for (int kt = 0; kt < 16; ++kt) {
    const int k0 = kt * 64;
    __syncthreads();
#pragma unroll
    for (int half = 0; half < 2; ++half) {
      const int r = ar + half * 64;
      const float4* src = (const float4*)(t + (size_t)(row0 + r) * 1024 + k0 + ac);
      float4 v0 = src[0], v1 = src[1], v2 = src[2], v3 = src[3];
      uint4 p0, p1;
      p0.x = packbf2(v0.x, v0.y); p0.y = packbf2(v0.z, v0.w);
      p0.z = packbf2(v1.x, v1.y); p0.w = packbf2(v1.z, v1.w);
      p1.x = packbf2(v2.x, v2.y); p1.y = packbf2(v2.z, v2.w);
      p1.z = packbf2(v3.x, v3.y); p1.w = packbf2(v3.z, v3.w);
      uint4* dst = (uint4*)(&As[r * 72 + ac]);
      dst[0] = p0; dst[1] = p1;
    }
    {
      const uint4* src = (const uint4*)(wtT + (size_t)(col0 + brn) * 1024 + k0 + bco);
      uint4 x0 = src[0], x1 = src[1], x2 = src[2], x3 = src[3];
      uint4* dst = (uint4*)(&Bs[brn * 72 + bco]);
      dst[0] = x0; dst[1] = x1; dst[2] = x2; dst[3] = x3;
    }
    __syncthreads();
#pragma unroll
    for (int kf = 0; kf < 2; ++kf) {
      bf16x8 af[4], bfr[4];
#pragma unroll
      for (int mi = 0; mi < 4; ++mi)
        af[mi] = *(const bf16x8*)(&As[(wm * 64 + mi * 16 + l15) * 72 + kf * 32 + lk * 8]);
#pragma unroll
      for (int ni = 0; ni < 4; ++ni)
        bfr[ni] = *(const bf16x8*)(&Bs[(wn * 64 + ni * 16 + l15) * 72 + kf * 32 + lk * 8]);
#pragma unroll
      for (int mi = 0; mi < 4; ++mi)
#pragma unroll
        for (int ni = 0; ni < 4; ++ni)
          acc[mi][ni] = __builtin_amdgcn_mfma_f32_16x16x32_bf16(af[mi], bfr[ni], acc[mi][ni], 0, 0, 0);
    }
  }

  const int b = row0 >> 11;
  float gv[4];
#pragma unroll
  for (int ni = 0; ni < 4; ++ni)
    gv[ni] = g[b * H_ + col0 + wn * 64 + ni * 16 + l15];
#pragma unroll
  for (int mi = 0; mi < 4; ++mi) {
#pragma unroll
    for (int r = 0; r < 4; ++r) {
      float s = 0.f;
#pragma unroll
      for (int ni = 0; ni < 4; ++ni)
        s += fast_tanh(acc[mi][ni][r]) * gv[ni];
      s += __shfl_xor(s, 1); s += __shfl_xor(s, 2);
      s += __shfl_xor(s, 4); s += __shfl_xor(s, 8);
      if (l15 == 0)
        red[wn * 128 + wm * 64 + mi * 16 + lk * 4 + r] = s;
    }
  }
  __syncthreads();
  if (tid < 128)
    spart[(size_t)bn * M_ + row0 + tid] = red[tid] + red[128 + tid];
}

// ---------------------------------------------------------------------------
// Softmax + mask + renormalize, with inline mask-layout detection.
// Detection: scan words [0,16384) (=64KB, safe for int32 or byte bools);
// any word >1 => byte-packed bools. Deterministic.
// ---------------------------------------------------------------------------
__global__ __launch_bounds__(256) void k_softmax(const float* __restrict__ spart,
                                                 const void* __restrict__ mask,
                                                 float* __restrict__ att) {
  __shared__ float redmax[4], redsum[4];
  __shared__ int shflag[4];
  const int b = blockIdx.x, tid = threadIdx.x;

  // mask layout detection
  {
    const unsigned int* mw = (const unsigned int*)mask;
    int any = 0;
    for (int i = tid; i < 16384; i += 256)
      if (mw[i] > 1u) any = 1;
    const int wa = __any(any) ? 1 : 0;
    if ((tid & 63) == 0) shflag[tid >> 6] = wa;
  }

  float s[8];
#pragma unroll
  for (int j = 0; j < 8; ++j) {
    const int idx = tid + j * 256;
    float v = 0.f;
#pragma unroll
    for (int nb = 0; nb < 8; ++nb) v += spart[(size_t)nb * M_ + b * T_ + idx];
    s[j] = v;
  }
  float mx = s[0];
#pragma unroll
  for (int j = 1; j < 8; ++j) mx = fmaxf(mx, s[j]);
  for (int o = 1; o < 64; o <<= 1) mx = fmaxf(mx, __shfl_xor(mx, o));
  if ((tid & 63) == 0) redmax[tid >> 6] = mx;
  __syncthreads();
  mx = fmaxf(fmaxf(redmax[0], redmax[1]), fmaxf(redmax[2], redmax[3]));
  const int byte_mode = shflag[0] | shflag[1] | shflag[2] | shflag[3];

  float e[8];
  float sum = 0.f;
#pragma unroll
  for (int j = 0; j < 8; ++j) {
    const int idx = tid + j * 256;
    float v = __expf(s[j] - mx);
    const int mv = byte_mode ? (int)((const unsigned char*)mask)[b * T_ + idx]
                             : ((const int*)mask)[b * T_ + idx];
    v = (mv != 0) ? v : 0.f;
    e[j] = v;
    sum += v;
  }
  for (int o = 1; o < 64; o <<= 1) sum += __shfl_xor(sum, o);
  if ((tid & 63) == 0) redsum[tid >> 6] = sum;
  __syncthreads();
  sum = redsum[0] + redsum[1] + redsum[2] + redsum[3];
  const float inv = 1.f / sum;
#pragma unroll
  for (int j = 0; j < 8; ++j)
    att[b * T_ + tid + j * 256] = e[j] * inv;
}

// ---------------------------------------------------------------------------
// Pooling on bf16 t (half the traffic): pp[tc][b][d] = sum att * tb
// Independent RNE errors average out under the att weights (~3e-5 std).
// ---------------------------------------------------------------------------
__global__ __launch_bounds__(256) void k_pool_bf(const unsigned short* __restrict__ tb,
                                                 const float* __restrict__ att,
                                                 float* __restrict__ pp) {
  const int b = blockIdx.x, tc = blockIdx.y, tid = threadIdx.x;
  const uint2* tp = (const uint2*)tb;
  float4 acc = make_float4(0.f, 0.f, 0.f, 0.f);
  const int tbase = tc * 128;
  for (int i = 0; i < 128; ++i) {
    const int ti = tbase + i;
    const float wv = att[b * T_ + ti];
    const uint2 v = tp[(size_t)(b * T_ + ti) * 256 + tid];
    acc.x += wv * bfu(v.x & 0xffffu);
    acc.y += wv * bfu(v.x >> 16);
    acc.z += wv * bfu(v.y & 0xffffu);
    acc.w += wv * bfu(v.y >> 16);
  }
  ((float4*)pp)[(size_t)tc * 8192 + b * 256 + tid] = acc;
}

// Fallback pooling on fp32 t.
__global__ __launch_bounds__(256) void k_pool_f32(const float* __restrict__ t,
                                                  const float* __restrict__ att,
                                                  float* __restrict__ pp) {
  const int b = blockIdx.x, tc = blockIdx.y, tid = threadIdx.x;
  const float4* tp = (const float4*)t;
  float4 acc = make_float4(0.f, 0.f, 0.f, 0.f);
  const int tbase = tc * 128;
  for (int i = 0; i < 128; ++i) {
    const int ti = tbase + i;
    const float w = att[b * T_ + ti];
    const float4 v = tp[(size_t)(b * T_ + ti) * 256 + tid];
    acc.x += w * v.x; acc.y += w * v.y; acc.z += w * v.z; acc.w += w * v.w;
  }
  ((float4*)pp)[(size_t)tc * 8192 + b * 256 + tid] = acc;
}

__global__ __launch_bounds__(256) void k_pool_reduce(const float* __restrict__ pp,
                                                     float* __restrict__ out) {
  const int idx = blockIdx.x * 256 + threadIdx.x;  // 0 .. 32767
  float s = 0.f;
#pragma unroll
  for (int tc = 0; tc < 16; ++tc) s += pp[tc * 32768 + idx];
  out[idx] = s;
}

// ---------------------------------------------------------------------------
extern "C" void kernel_launch(void* const* d_in, const int* in_sizes, int n_in,
                              void* d_out, int out_size, void* d_ws, size_t ws_size,
                              hipStream_t stream) {
  const float* t    = (const float*)d_in[0];
  const float* a    = (const float*)d_in[1];
  const float* b    = (const float*)d_in[2];
  const void*  mask = d_in[3];
  const float* wt   = (const float*)d_in[4];
  const float* wa   = (const float*)d_in[5];
  const float* wb   = (const float*)d_in[6];
  const float* wh   = (const float*)d_in[7];
  float* out = (float*)d_out;

  // fast ws layout (float units):
  //   tb[33554432 ushort -> 16777216 f] ... use element counts in floats:
  //   tb: 33554432 ushort = 16777216 floats? NO: 64M bf16 = 128MB = 33554432 floats/2...
  //   64M elements * 2B = 128MB = 33554432 float-slots? 128MB/4 = 33554432. Yes.
  float* ws = (float*)d_ws;
  const size_t NEED_FAST = (size_t)(33554432 + 32768 + 65536 + 524288 + 524288 + 524288) * 4;
  const bool fast = ws_size >= NEED_FAST;

  if (fast) {
    unsigned short* tb = (unsigned short*)ws;          // 128 MB
    float* g     = ws + 33554432;
    float* att   = g + 32768;
    float* spart = att + 65536;
    float* pp    = spart + 524288;
    unsigned short* wtT = (unsigned short*)(pp + 524288);

    k_wt_transpose<<<dim3(32, 32), 256, 0, stream>>>(wt, wtT);
    k_tobf16<<<4096, 256, 0, stream>>>((const float4*)t, (uint2*)tb);
    k_g<<<128, 256, 0, stream>>>(a, b, wa, wb, wh, g);
    k_score_fast<<<2048, 512, 0, stream>>>(tb, wtT, g, spart);
    k_softmax<<<32, 256, 0, stream>>>(spart, mask, att);
    k_pool_bf<<<dim3(32, 16), 256, 0, stream>>>(tb, att, pp);
    k_pool_reduce<<<128, 256, 0, stream>>>(pp, out);
  } else {
    float* g     = ws;
    float* att   = ws + 32768;
    float* spart = ws + 98304;
    float* pp    = ws + 622592;
    unsigned short* wtT = (unsigned short*)(ws + 1146880);

    k_wt_transpose<<<dim3(32, 32), 256, 0, stream>>>(wt, wtT);
    k_g<<<128, 256, 0, stream>>>(a, b, wa, wb, wh, g);
    k_score_rs<<<dim3(8, 512), 256, 0, stream>>>(t, wtT, g, spart);
    k_softmax<<<32, 256, 0, stream>>>(spart, mask, att);
    k_pool_f32<<<dim3(32, 16), 256, 0, stream>>>(t, att, pp);
    k_pool_reduce<<<128, 256, 0, stream>>>(pp, out);
  }
}

// Round 5
// 337.392 us; speedup vs baseline: 1.3523x; 1.1228x over previous
//
#include <hip/hip_runtime.h>
#include <hip/hip_bf16.h>
#include <cstdint>
#include <cstddef>

#define B_  32
#define T_  2048
#define D_  1024
#define H_  1024
#define M_  (B_ * T_)   // 65536 rows of t

typedef __attribute__((ext_vector_type(4))) float  f32x4;
typedef __attribute__((ext_vector_type(8))) __bf16 bf16x8;

#define GLOBAL_AS __attribute__((address_space(1)))
#define LDS_AS    __attribute__((address_space(3)))

__device__ __forceinline__ void gload_lds16(const void* g, void* l) {
  __builtin_amdgcn_global_load_lds((const GLOBAL_AS unsigned int*)g,
                                   (LDS_AS unsigned int*)l, 16, 0, 0);
}

__device__ __forceinline__ unsigned int f2bf(float f) {
  unsigned int u = __float_as_uint(f);
  return (u + 0x7fffu + ((u >> 16) & 1u)) >> 16;   // RNE
}
__device__ __forceinline__ unsigned int packbf2(float lo, float hi) {
  return f2bf(lo) | (f2bf(hi) << 16);
}
__device__ __forceinline__ float bfu(unsigned int u) {   // bf16 bits (low 16) -> f32
  return __uint_as_float(u << 16);
}
__device__ __forceinline__ float fast_tanh(float x) {
  x = fminf(fmaxf(x, -15.f), 15.f);
  float e = __expf(2.f * x);
  return (e - 1.f) / (e + 1.f);
}

// ---------------------------------------------------------------------------
// t (fp32) -> t_bf16, memory-bound streaming pass. 64M elements.
// ---------------------------------------------------------------------------
__global__ __launch_bounds__(256) void k_tobf16(const float4* __restrict__ t4,
                                                uint2* __restrict__ ob) {
  const size_t stride = (size_t)gridDim.x * 256;
  for (size_t i = (size_t)blockIdx.x * 256 + threadIdx.x; i < (size_t)M_ * 256; i += stride) {
    const float4 v = t4[i];
    uint2 o; o.x = packbf2(v.x, v.y); o.y = packbf2(v.z, v.w);
    ob[i] = o;
  }
}

// ---------------------------------------------------------------------------
// wt (D x H fp32, row-major) -> wtT (H x D bf16, row-major)  [2 MB out]
// ---------------------------------------------------------------------------
__global__ __launch_bounds__(256) void k_wt_transpose(const float* __restrict__ wt,
                                                      unsigned short* __restrict__ wtT) {
  __shared__ float tile[32][33];
  const int tx = threadIdx.x & 31, ty = threadIdx.x >> 5;  // 32 x 8
  const int c0 = blockIdx.x * 32, r0 = blockIdx.y * 32;
#pragma unroll
  for (int i = 0; i < 4; ++i)
    tile[ty + i * 8][tx] = wt[(size_t)(r0 + ty + i * 8) * H_ + c0 + tx];
  __syncthreads();
#pragma unroll
  for (int i = 0; i < 4; ++i)
    wtT[(size_t)(c0 + ty + i * 8) * D_ + r0 + tx] = (unsigned short)f2bf(tile[tx][ty + i * 8]);
}

// ---------------------------------------------------------------------------
// g[b,h] = tanh(a[b]@wa[:,h]) * tanh(b[b]@wb[:,h]) * wh[h]
// ---------------------------------------------------------------------------
__global__ __launch_bounds__(256) void k_g(const float* __restrict__ a,
                                           const float* __restrict__ b,
                                           const float* __restrict__ wa,
                                           const float* __restrict__ wb,
                                           const float* __restrict__ wh,
                                           float* __restrict__ g) {
  const int idx = blockIdx.x * 256 + threadIdx.x;   // 0 .. 32767
  const int bb = idx >> 10, h = idx & 1023;
  float sa = 0.f, sb = 0.f;
  for (int d = 0; d < 1024; ++d) {
    sa += a[bb * 1024 + d] * wa[d * 1024 + h];
    sb += b[bb * 1024 + d] * wb[d * 1024 + h];
  }
  g[idx] = fast_tanh(sa) * fast_tanh(sb) * wh[h];
}

// ---------------------------------------------------------------------------
// FAST fused score GEMM: 256x128 tile, BK=64, 8 waves (4M x 2N), 512 threads.
// global_load_lds width-16 staging with T2 XOR-swizzle done BOTH-SIDES
// (rule #21): LDS dest stays linear; the per-lane GLOBAL source chunk is
// pre-permuted (chunk ^= row&7), and the ds_read applies the same XOR.
// LDS[row][c] = global[row][c ^ (row&7)]  (16B chunks, involution).
// XCD-bijective swizzle on the grid (2048 wgs, 2048%8==0).
// spart[bn][row] = sum_{h in bn-block} tanh((t@wt)[row,h]) * g[b,h]
// ---------------------------------------------------------------------------
__global__ __launch_bounds__(512) void k_score_fast(const unsigned short* __restrict__ tb,
                                                    const unsigned short* __restrict__ wtT,
                                                    const float* __restrict__ g,
                                                    float* __restrict__ spart) {
  __shared__ unsigned short As[256 * 64];   // 32 KB  [row][k] linear+swz
  __shared__ unsigned short Bs[128 * 64];   // 16 KB  [n][k]  linear+swz
  __shared__ float red[512];                // [wn][256 rows]
  const int tid = threadIdx.x;
  const int wg  = (blockIdx.x & 7) * 256 + (blockIdx.x >> 3);  // bijective
  const int bm2 = wg >> 3, bn = wg & 7;
  const int lane = tid & 63, w = tid >> 6;       // 8 waves
  const int wm = w >> 1, wn = w & 1;             // 4 x 2
  const int l15 = lane & 15, lk = lane >> 4;
  const int axk = l15 & 7;                       // read-side XOR key
  const int row0 = bm2 * 256, col0 = bn * 128;

  // staging: wave-uniform LDS base + lane*16B linear dest (gload_lds req).
  // global source chunk pre-swizzled: chunk = (lane&7) ^ srow, srow = lane>>3.
  const int srow = lane >> 3;                    // 8 rows per 1KB issue
  const int scol = (((lane & 7) ^ srow) * 8);    // swizzled 16B chunk
  const unsigned short* gA = tb  + (size_t)(row0 + w * 32 + srow) * 1024 + scol;
  const unsigned short* gB = wtT + (size_t)(col0 + w * 16 + srow) * 1024 + scol;
  unsigned short* lA = &As[(w * 32) * 64];
  unsigned short* lB = &Bs[(w * 16) * 64];

  f32x4 acc[4][4] = {};

  for (int kt = 0; kt < 16; ++kt) {
    const int k0 = kt * 64;
    __syncthreads();   // previous iteration's LDS reads done
#pragma unroll
    for (int i = 0; i < 4; ++i)   // A: rows w*32 + i*8 .. +8
      gload_lds16(gA + (size_t)i * 8192 + k0, lA + i * 512);
#pragma unroll
    for (int j = 0; j < 2; ++j)   // B: rows w*16 + j*8 .. +8
      gload_lds16(gB + (size_t)j * 8192 + k0, lB + j * 512);
    __syncthreads();   // compiler drains vmcnt(0) before this barrier
#pragma unroll
    for (int kf = 0; kf < 2; ++kf) {
      bf16x8 af[4], bfr[4];
#pragma unroll
      for (int mi = 0; mi < 4; ++mi)
        af[mi] = *(const bf16x8*)(&As[(wm * 64 + mi * 16 + l15) * 64
                                      + (((kf * 4 + lk) ^ axk) << 3)]);
#pragma unroll
      for (int ni = 0; ni < 4; ++ni)
        bfr[ni] = *(const bf16x8*)(&Bs[(wn * 64 + ni * 16 + l15) * 64
                                       + (((kf * 4 + lk) ^ axk) << 3)]);
#pragma unroll
      for (int mi = 0; mi < 4; ++mi)
#pragma unroll
        for (int ni = 0; ni < 4; ++ni)
          acc[mi][ni] = __builtin_amdgcn_mfma_f32_16x16x32_bf16(af[mi], bfr[ni], acc[mi][ni], 0, 0, 0);
    }
  }

  // ---- epilogue: tanh, * g[b,h], reduce over this block's 128 h-columns
  const int b = row0 >> 11;  // 256-row tile never crosses a b-boundary
  float gv[4];
#pragma unroll
  for (int ni = 0; ni < 4; ++ni)
    gv[ni] = g[b * H_ + col0 + wn * 64 + ni * 16 + l15];
#pragma unroll
  for (int mi = 0; mi < 4; ++mi) {
#pragma unroll
    for (int r = 0; r < 4; ++r) {
      float s = 0.f;
#pragma unroll
      for (int ni = 0; ni < 4; ++ni)
        s += fast_tanh(acc[mi][ni][r]) * gv[ni];
      s += __shfl_xor(s, 1); s += __shfl_xor(s, 2);
      s += __shfl_xor(s, 4); s += __shfl_xor(s, 8);
      if (l15 == 0)
        red[wn * 256 + wm * 64 + mi * 16 + lk * 4 + r] = s;
    }
  }
  __syncthreads();
  if (tid < 256)
    spart[(size_t)bn * M_ + row0 + tid] = red[tid] + red[256 + tid];
}

// ---------------------------------------------------------------------------
// Fallback fused score GEMM (reg-staged fp32->bf16), used if ws too small.
// ---------------------------------------------------------------------------
__global__ __launch_bounds__(256) void k_score_rs(const float* __restrict__ t,
                                                  const unsigned short* __restrict__ wtT,
                                                  const float* __restrict__ g,
                                                  float* __restrict__ spart) {
  __shared__ unsigned short As[128 * 72];
  __shared__ unsigned short Bs[128 * 72];
  __shared__ float red[256];
  const int tid = threadIdx.x;
  const int bn = blockIdx.x, bm = blockIdx.y;
  const int lane = tid & 63, w = tid >> 6;
  const int wm = w >> 1, wn = w & 1;
  const int l15 = lane & 15, lk = lane >> 4;
  const int row0 = bm * 128, col0 = bn * 128;
  const int ar = tid >> 2, ac = (tid & 3) * 16;
  const int brn = tid >> 1, bco = (tid & 1) * 32;

  f32x4 acc[4][4] = {};

  for (int kt = 0; kt < 16; ++kt) {
    const int k0 = kt * 64;
    __syncthreads();
#pragma unroll
    for (int half = 0; half < 2; ++half) {
      const int r = ar + half * 64;
      const float4* src = (const float4*)(t + (size_t)(row0 + r) * 1024 + k0 + ac);
      float4 v0 = src[0], v1 = src[1], v2 = src[2], v3 = src[3];
      uint4 p0, p1;
      p0.x = packbf2(v0.x, v0.y); p0.y = packbf2(v0.z, v0.w);
      p0.z = packbf2(v1.x, v1.y); p0.w = packbf2(v1.z, v1.w);
      p1.x = packbf2(v2.x, v2.y); p1.y = packbf2(v2.z, v2.w);
      p1.z = packbf2(v3.x, v3.y); p1.w = packbf2(v3.z, v3.w);
      uint4* dst = (uint4*)(&As[r * 72 + ac]);
      dst[0] = p0; dst[1] = p1;
    }
    {
      const uint4* src = (const uint4*)(wtT + (size_t)(col0 + brn) * 1024 + k0 + bco);
      uint4 x0 = src[0], x1 = src[1], x2 = src[2], x3 = src[3];
      uint4* dst = (uint4*)(&Bs[brn * 72 + bco]);
      dst[0] = x0; dst[1] = x1; dst[2] = x2; dst[3] = x3;
    }
    __syncthreads();
#pragma unroll
    for (int kf = 0; kf < 2; ++kf) {
      bf16x8 af[4], bfr[4];
#pragma unroll
      for (int mi = 0; mi < 4; ++mi)
        af[mi] = *(const bf16x8*)(&As[(wm * 64 + mi * 16 + l15) * 72 + kf * 32 + lk * 8]);
#pragma unroll
      for (int ni = 0; ni < 4; ++ni)
        bfr[ni] = *(const bf16x8*)(&Bs[(wn * 64 + ni * 16 + l15) * 72 + kf * 32 + lk * 8]);
#pragma unroll
      for (int mi = 0; mi < 4; ++mi)
#pragma unroll
        for (int ni = 0; ni < 4; ++ni)
          acc[mi][ni] = __builtin_amdgcn_mfma_f32_16x16x32_bf16(af[mi], bfr[ni], acc[mi][ni], 0, 0, 0);
    }
  }

  const int b = row0 >> 11;
  float gv[4];
#pragma unroll
  for (int ni = 0; ni < 4; ++ni)
    gv[ni] = g[b * H_ + col0 + wn * 64 + ni * 16 + l15];
#pragma unroll
  for (int mi = 0; mi < 4; ++mi) {
#pragma unroll
    for (int r = 0; r < 4; ++r) {
      float s = 0.f;
#pragma unroll
      for (int ni = 0; ni < 4; ++ni)
        s += fast_tanh(acc[mi][ni][r]) * gv[ni];
      s += __shfl_xor(s, 1); s += __shfl_xor(s, 2);
      s += __shfl_xor(s, 4); s += __shfl_xor(s, 8);
      if (l15 == 0)
        red[wn * 128 + wm * 64 + mi * 16 + lk * 4 + r] = s;
    }
  }
  __syncthreads();
  if (tid < 128)
    spart[(size_t)bn * M_ + row0 + tid] = red[tid] + red[128 + tid];
}

// ---------------------------------------------------------------------------
// Softmax + mask + renormalize, with inline mask-layout detection.
// ---------------------------------------------------------------------------
__global__ __launch_bounds__(256) void k_softmax(const float* __restrict__ spart,
                                                 const void* __restrict__ mask,
                                                 float* __restrict__ att) {
  __shared__ float redmax[4], redsum[4];
  __shared__ int shflag[4];
  const int b = blockIdx.x, tid = threadIdx.x;

  // mask layout detection (int32 {0,1} vs byte-packed bools)
  {
    const unsigned int* mw = (const unsigned int*)mask;
    int any = 0;
    for (int i = tid; i < 16384; i += 256)
      if (mw[i] > 1u) any = 1;
    const int wa = __any(any) ? 1 : 0;
    if ((tid & 63) == 0) shflag[tid >> 6] = wa;
  }

  float s[8];
#pragma unroll
  for (int j = 0; j < 8; ++j) {
    const int idx = tid + j * 256;
    float v = 0.f;
#pragma unroll
    for (int nb = 0; nb < 8; ++nb) v += spart[(size_t)nb * M_ + b * T_ + idx];
    s[j] = v;
  }
  float mx = s[0];
#pragma unroll
  for (int j = 1; j < 8; ++j) mx = fmaxf(mx, s[j]);
  for (int o = 1; o < 64; o <<= 1) mx = fmaxf(mx, __shfl_xor(mx, o));
  if ((tid & 63) == 0) redmax[tid >> 6] = mx;
  __syncthreads();
  mx = fmaxf(fmaxf(redmax[0], redmax[1]), fmaxf(redmax[2], redmax[3]));
  const int byte_mode = shflag[0] | shflag[1] | shflag[2] | shflag[3];

  float e[8];
  float sum = 0.f;
#pragma unroll
  for (int j = 0; j < 8; ++j) {
    const int idx = tid + j * 256;
    float v = __expf(s[j] - mx);
    const int mv = byte_mode ? (int)((const unsigned char*)mask)[b * T_ + idx]
                             : ((const int*)mask)[b * T_ + idx];
    v = (mv != 0) ? v : 0.f;
    e[j] = v;
    sum += v;
  }
  for (int o = 1; o < 64; o <<= 1) sum += __shfl_xor(sum, o);
  if ((tid & 63) == 0) redsum[tid >> 6] = sum;
  __syncthreads();
  sum = redsum[0] + redsum[1] + redsum[2] + redsum[3];
  const float inv = 1.f / sum;
#pragma unroll
  for (int j = 0; j < 8; ++j)
    att[b * T_ + tid + j * 256] = e[j] * inv;
}

// ---------------------------------------------------------------------------
// Pooling on bf16 t (half the traffic): pp[tc][b][d] = sum att * tb
// ---------------------------------------------------------------------------
__global__ __launch_bounds__(256) void k_pool_bf(const unsigned short* __restrict__ tb,
                                                 const float* __restrict__ att,
                                                 float* __restrict__ pp) {
  const int b = blockIdx.x, tc = blockIdx.y, tid = threadIdx.x;
  const uint2* tp = (const uint2*)tb;
  float4 acc = make_float4(0.f, 0.f, 0.f, 0.f);
  const int tbase = tc * 128;
  for (int i = 0; i < 128; ++i) {
    const int ti = tbase + i;
    const float wv = att[b * T_ + ti];
    const uint2 v = tp[(size_t)(b * T_ + ti) * 256 + tid];
    acc.x += wv * bfu(v.x & 0xffffu);
    acc.y += wv * bfu(v.x >> 16);
    acc.z += wv * bfu(v.y & 0xffffu);
    acc.w += wv * bfu(v.y >> 16);
  }
  ((float4*)pp)[(size_t)tc * 8192 + b * 256 + tid] = acc;
}

// Fallback pooling on fp32 t.
__global__ __launch_bounds__(256) void k_pool_f32(const float* __restrict__ t,
                                                  const float* __restrict__ att,
                                                  float* __restrict__ pp) {
  const int b = blockIdx.x, tc = blockIdx.y, tid = threadIdx.x;
  const float4* tp = (const float4*)t;
  float4 acc = make_float4(0.f, 0.f, 0.f, 0.f);
  const int tbase = tc * 128;
  for (int i = 0; i < 128; ++i) {
    const int ti = tbase + i;
    const float w = att[b * T_ + ti];
    const float4 v = tp[(size_t)(b * T_ + ti) * 256 + tid];
    acc.x += w * v.x; acc.y += w * v.y; acc.z += w * v.z; acc.w += w * v.w;
  }
  ((float4*)pp)[(size_t)tc * 8192 + b * 256 + tid] = acc;
}

__global__ __launch_bounds__(256) void k_pool_reduce(const float* __restrict__ pp,
                                                     float* __restrict__ out) {
  const int idx = blockIdx.x * 256 + threadIdx.x;  // 0 .. 32767
  float s = 0.f;
#pragma unroll
  for (int tc = 0; tc < 16; ++tc) s += pp[tc * 32768 + idx];
  out[idx] = s;
}

// ---------------------------------------------------------------------------
extern "C" void kernel_launch(void* const* d_in, const int* in_sizes, int n_in,
                              void* d_out, int out_size, void* d_ws, size_t ws_size,
                              hipStream_t stream) {
  const float* t    = (const float*)d_in[0];
  const float* a    = (const float*)d_in[1];
  const float* b    = (const float*)d_in[2];
  const void*  mask = d_in[3];
  const float* wt   = (const float*)d_in[4];
  const float* wa   = (const float*)d_in[5];
  const float* wb   = (const float*)d_in[6];
  const float* wh   = (const float*)d_in[7];
  float* out = (float*)d_out;

  float* ws = (float*)d_ws;
  const size_t NEED_FAST = (size_t)(33554432 + 32768 + 65536 + 524288 + 524288 + 524288) * 4;
  const bool fast = ws_size >= NEED_FAST;

  if (fast) {
    unsigned short* tb = (unsigned short*)ws;          // 128 MB
    float* g     = ws + 33554432;
    float* att   = g + 32768;
    float* spart = att + 65536;
    float* pp    = spart + 524288;
    unsigned short* wtT = (unsigned short*)(pp + 524288);

    k_wt_transpose<<<dim3(32, 32), 256, 0, stream>>>(wt, wtT);
    k_tobf16<<<4096, 256, 0, stream>>>((const float4*)t, (uint2*)tb);
    k_g<<<128, 256, 0, stream>>>(a, b, wa, wb, wh, g);
    k_score_fast<<<2048, 512, 0, stream>>>(tb, wtT, g, spart);
    k_softmax<<<32, 256, 0, stream>>>(spart, mask, att);
    k_pool_bf<<<dim3(32, 16), 256, 0, stream>>>(tb, att, pp);
    k_pool_reduce<<<128, 256, 0, stream>>>(pp, out);
  } else {
    float* g     = ws;
    float* att   = ws + 32768;
    float* spart = ws + 98304;
    float* pp    = ws + 622592;
    unsigned short* wtT = (unsigned short*)(ws + 1146880);

    k_wt_transpose<<<dim3(32, 32), 256, 0, stream>>>(wt, wtT);
    k_g<<<128, 256, 0, stream>>>(a, b, wa, wb, wh, g);
    k_score_rs<<<dim3(8, 512), 256, 0, stream>>>(t, wtT, g, spart);
    k_softmax<<<32, 256, 0, stream>>>(spart, mask, att);
    k_pool_f32<<<dim3(32, 16), 256, 0, stream>>>(t, att, pp);
    k_pool_reduce<<<128, 256, 0, stream>>>(pp, out);
  }
}